// Round 3
// baseline (441.094 us; speedup 1.0000x reference)
//
#include <hip/hip_runtime.h>
#include <hip/hip_bf16.h>
#include <math.h>

#define BS   32
#define T    512
#define BT   (BS * T)      // 16384 tokens
#define D    96
#define H    4
#define MX   32            // DST_MXLEN

// ---------------------------------------------------------------------------
// Kernel 1: QKV projection (fp32 in, fp32 out). Only channels 32..95 of each
// of q,k,v are consumed downstream (b[:, :, 0:32] is hard zeros), so compute
// 64*3 = 192 outputs per token instead of 288. One block per token; x row
// staged in LDS. Q/K/V layout: [(b*T + t)*64 + (channel - 32)], fp32.
// ---------------------------------------------------------------------------
__global__ void qkv_kernel(const float* __restrict__ x, const float* __restrict__ w,
                           float* __restrict__ Q, float* __restrict__ K,
                           float* __restrict__ V) {
    const int token = blockIdx.x;
    const int tid   = threadIdx.x;       // 192 threads
    __shared__ float xs[D];
    if (tid < D) xs[tid] = x[token * D + tid];
    __syncthreads();
    const int c    = tid & 63;           // 0..63  -> channel 32+c
    const int part = tid >> 6;           // 0=q 1=k 2=v
    const int o    = part * 96 + 32 + c; // row in wqv_w (288 x 97)
    const float* wr = w + o * 97;
    float acc = wr[96];                  // bias
    #pragma unroll 8
    for (int i = 0; i < D; ++i) acc += wr[i] * xs[i];
    float* out = (part == 0) ? Q : (part == 1 ? K : V);
    out[token * 64 + c] = acc;
}

// ---------------------------------------------------------------------------
// Kernel 2: scatter COO rows into a dense per-(token, slot) src table.
// srcs[ci*T*MX + dst*MX + cnt] = src ; unwritten slots stay -1 (memset 0xFF)
// which reproduces the reference's -1e12 fill (softmax weight 0).
// ---------------------------------------------------------------------------
__global__ void scatter_kernel(const int* __restrict__ coo0,
                               const int* __restrict__ coo1,
                               int* __restrict__ srcs, int nedges) {
    const int id = blockIdx.x * blockDim.x + threadIdx.x;
    if (id >= 2 * nedges) return;
    const int ci = id / nedges;
    const int e  = id - ci * nedges;
    const int* row = (ci == 0 ? coo0 : coo1) + e * 3;
    const int dst = row[0], src = row[1], cnt = row[2];
    if (dst >= 0 && dst < T && cnt >= 0 && cnt < MX)
        srcs[ci * T * MX + dst * MX + cnt] = src;
}

// ---------------------------------------------------------------------------
// Kernel 3: sparse L1 attention. One thread per (coo, b, t, head).
// All logits are <= 0 (-L1/sqrt(5)) so exp() cannot overflow -> single-pass
// unnormalized softmax + weighted V accumulation, divide at the end.
// coo i uses channels sta=32+20i .. sta+20 -> Q-array base 20*i + h*5.
// ---------------------------------------------------------------------------
__global__ void sparse_kernel(const float* __restrict__ Q, const float* __restrict__ K,
                              const float* __restrict__ V, const int* __restrict__ srcs,
                              float* __restrict__ B) {
    const int id = blockIdx.x * blockDim.x + threadIdx.x;   // 2*BT*H = 131072
    const int h  = id & 3;
    const int bt = (id >> 2) & (BT - 1);
    const int ci = id >> 16;                                 // BT*H == 65536
    const int b  = bt >> 9;
    const int base = 20 * ci + h * 5;
    const int t  = bt & (T - 1);
    const int* sp  = srcs + ci * T * MX + t * MX;
    const float* qp = Q + bt * 64 + base;
    const float q0 = qp[0], q1 = qp[1], q2 = qp[2], q3 = qp[3], q4 = qp[4];
    const float iscale = 0.4472135954999579f;                // 1/sqrt(5)
    float l = 0.f, o0 = 0.f, o1 = 0.f, o2 = 0.f, o3 = 0.f, o4 = 0.f;
    #pragma unroll 4
    for (int c = 0; c < MX; ++c) {
        const int s = sp[c];
        if (s < 0) continue;                                 // empty slot (-1e12)
        const float* kp = K + (b * T + s) * 64 + base;
        float sum = fabsf(q0 - kp[0]) + fabsf(q1 - kp[1]) + fabsf(q2 - kp[2]) +
                    fabsf(q3 - kp[3]) + fabsf(q4 - kp[4]);
        const float e = expf(-sum * iscale);
        const float* vp = V + (b * T + s) * 64 + base;
        l  += e;
        o0 += e * vp[0]; o1 += e * vp[1]; o2 += e * vp[2];
        o3 += e * vp[3]; o4 += e * vp[4];
    }
    const float inv = (l > 0.f) ? 1.f / l : 0.f;
    float* bp = B + bt * 96 + 32 + base;
    bp[0] = o0 * inv; bp[1] = o1 * inv; bp[2] = o2 * inv;
    bp[3] = o3 * inv; bp[4] = o4 * inv;
}

// ---------------------------------------------------------------------------
// Kernel 4: dense L1 attention over the a2len a2a-selected tokens,
// channels 72..95 (h*6). Softmax denominator includes the zero-pad key
// (row at index a2len, present because padl > a2len): exp(-|q|_1/sqrt(6)).
// One thread per (b, d, h); streaming softmax (logits <= 0).
// ---------------------------------------------------------------------------
__global__ void dense_kernel(const float* __restrict__ Q, const float* __restrict__ K,
                             const float* __restrict__ V, const int* __restrict__ a2a,
                             int a2len, int extra, float* __restrict__ B) {
    const int id = blockIdx.x * blockDim.x + threadIdx.x;
    if (id >= BS * 150 * H) return;
    const int h    = id & 3;
    const int rest = id >> 2;
    const int d    = rest % a2len;
    const int b    = rest / a2len;
    const int td   = a2a[d];
    const float scale = 0.4082482904638631f;                 // 1/sqrt(6)
    const float* qp = Q + (b * T + td) * 64 + 40 + h * 6;    // channel 72 -> idx 40
    float q[6];
    #pragma unroll
    for (int w = 0; w < 6; ++w) q[w] = qp[w];
    float l = 0.f, o[6] = {0.f, 0.f, 0.f, 0.f, 0.f, 0.f};
    for (int s = 0; s < a2len; ++s) {
        const int ts = a2a[s];
        const float* kp = K + (b * T + ts) * 64 + 40 + h * 6;
        float sum = 0.f;
        #pragma unroll
        for (int w = 0; w < 6; ++w) sum += fabsf(q[w] - kp[w]);
        const float e = expf(-sum * scale);
        l += e;
        const float* vp = V + (b * T + ts) * 64 + 40 + h * 6;
        #pragma unroll
        for (int w = 0; w < 6; ++w) o[w] += e * vp[w];
    }
    if (extra) {                                             // zero-pad key row
        float sum = 0.f;
        #pragma unroll
        for (int w = 0; w < 6; ++w) sum += fabsf(q[w]);
        l += expf(-sum * scale);
    }
    const float inv = 1.f / l;
    float* bp = B + (b * T + td) * 96 + 72 + h * 6;
    #pragma unroll
    for (int w = 0; w < 6; ++w) bp[w] = o[w] * inv;
}

// ---------------------------------------------------------------------------
// Kernel 5: yb = b * sigmoid(1.702*b); out = x + fanout_w[:, :96] @ yb + bias.
// One block per token, yb staged in LDS. Output is fp32 (reference dtype).
// ---------------------------------------------------------------------------
__global__ void fuse_kernel(const float* __restrict__ x, const float* __restrict__ fw,
                            const float* __restrict__ B, float* __restrict__ out) {
    const int token = blockIdx.x;
    const int tid   = threadIdx.x;        // 128 threads, 96 active
    __shared__ float yb[D];
    if (tid < D) {
        const float v = B[token * D + tid];
        yb[tid] = v / (1.f + expf(-1.702f * v));
    }
    __syncthreads();
    if (tid < D) {
        const float* wr = fw + tid * 97;
        float acc = wr[96];
        #pragma unroll 8
        for (int i = 0; i < D; ++i) acc += wr[i] * yb[i];
        out[token * D + tid] = x[token * D + tid] + acc;
    }
}

// ---------------------------------------------------------------------------
extern "C" void kernel_launch(void* const* d_in, const int* in_sizes, int n_in,
                              void* d_out, int out_size, void* d_ws, size_t ws_size,
                              hipStream_t stream) {
    const float* x   = (const float*)d_in[0];
    const float* wqv = (const float*)d_in[1];
    const float* fw  = (const float*)d_in[2];
    const int*  coo0 = (const int*)d_in[3];
    const int*  coo1 = (const int*)d_in[4];
    const int*  a2a  = (const int*)d_in[5];
    const int a2len  = in_sizes[5];            // 150
    const int nedges = in_sizes[3] / 3;        // 16384

    // Workspace layout (fp32): Q | K | V | B | srcs(int)   (~19 MB total)
    float* Q  = (float*)d_ws;
    float* K  = Q + (size_t)BT * 64;
    float* V  = K + (size_t)BT * 64;
    float* Bb = V + (size_t)BT * 64;
    int* srcs = (int*)(Bb + (size_t)BT * 96);

    hipMemsetAsync(srcs, 0xFF, 2 * T * MX * sizeof(int), stream);  // -1 = empty
    hipMemsetAsync(Bb, 0, (size_t)BT * 96 * sizeof(float), stream);

    qkv_kernel<<<BT, 192, 0, stream>>>(x, wqv, Q, K, V);
    scatter_kernel<<<(2 * nedges + 255) / 256, 256, 0, stream>>>(coo0, coo1, srcs, nedges);
    sparse_kernel<<<(2 * BT * H) / 256, 256, 0, stream>>>(Q, K, V, srcs, Bb);
    const int padl  = (a2len + 15) / 16 * 16;
    const int extra = (padl > a2len) ? 1 : 0;
    dense_kernel<<<(BS * a2len * H + 255) / 256, 256, 0, stream>>>(Q, K, V, a2a, a2len, extra, Bb);
    fuse_kernel<<<BT, 128, 0, stream>>>(x, fw, Bb, (float*)d_out);
}

// Round 4
// 187.698 us; speedup vs baseline: 2.3500x; 2.3500x over previous
//
#include <hip/hip_runtime.h>
#include <hip/hip_bf16.h>
#include <math.h>

#define BS   32
#define T    512
#define BT   (BS * T)      // 16384 tokens
#define D    96
#define H    4
#define MX   32            // DST_MXLEN

#define QKV_TOK  8         // tokens per qkv block
#define FUSE_TOK 8         // tokens per fuse block

// ---------------------------------------------------------------------------
// Kernel 0: one-time weight transposes into workspace (both tiny).
// WT  [97][192]: WT[i*192 + p*64 + c] = wqv[(p*96+32+c)*97 + i]  (i=96 -> bias)
// FWT [65][96] : FWT[i*96 + o]        = fw[o*97 + 32 + i]        (i=64 -> bias)
// Only rows 32..95 of each part are kept (channels 0..31 are never consumed).
// ---------------------------------------------------------------------------
__global__ void transpose_kernel(const float* __restrict__ wqv,
                                 const float* __restrict__ fw,
                                 float* __restrict__ WT, float* __restrict__ FWT) {
    int idx = blockIdx.x * blockDim.x + threadIdx.x;
    if (idx < 97 * 192) {
        const int i = idx / 192, oc = idx - 192 * i;
        const int p = oc >> 6, c = oc & 63;
        WT[idx] = wqv[(p * 96 + 32 + c) * 97 + i];
    }
    idx -= 97 * 192;
    if (idx >= 0 && idx < 65 * 96) {
        const int i = idx / 96, o = idx - 96 * i;
        FWT[idx] = fw[o * 97 + 32 + i];
    }
}

// ---------------------------------------------------------------------------
// Kernel 1: QKV projection, register-blocked. 192 threads x 8 tokens/block.
// Inner loop: ONE coalesced weight load (WT[i*192+tid], L2-resident) feeds
// 8 FMAs (x broadcast from LDS). Q/K/V layout: [(b*T+t)*64 + (ch-32)], fp32.
// ---------------------------------------------------------------------------
__global__ void qkv_kernel(const float* __restrict__ x, const float* __restrict__ WT,
                           float* __restrict__ Q, float* __restrict__ K,
                           float* __restrict__ V) {
    const int tid  = threadIdx.x;              // 0..191
    const int base = blockIdx.x * QKV_TOK;     // grid = BT/QKV_TOK
    __shared__ float xs[QKV_TOK * D];          // 768 floats
    #pragma unroll
    for (int j = 0; j < 4; ++j) xs[tid + 192 * j] = x[base * D + tid + 192 * j];
    __syncthreads();
    float acc[QKV_TOK];
    const float bias = WT[96 * 192 + tid];
    #pragma unroll
    for (int j = 0; j < QKV_TOK; ++j) acc[j] = bias;
    #pragma unroll 4
    for (int i = 0; i < D; ++i) {
        const float wv = WT[i * 192 + tid];
        #pragma unroll
        for (int j = 0; j < QKV_TOK; ++j) acc[j] += wv * xs[j * D + i];
    }
    const int part = tid >> 6, c = tid & 63;
    float* out = (part == 0) ? Q : (part == 1 ? K : V);
    #pragma unroll
    for (int j = 0; j < QKV_TOK; ++j) out[(base + j) * 64 + c] = acc[j];
}

// ---------------------------------------------------------------------------
// Kernel 2: scatter COO rows into a dense per-(token, slot) src table.
// srcs[ci*T*MX + dst*MX + cnt] = src ; unwritten slots stay -1 (memset 0xFF).
// ---------------------------------------------------------------------------
__global__ void scatter_kernel(const int* __restrict__ coo0,
                               const int* __restrict__ coo1,
                               int* __restrict__ srcs, int nedges) {
    const int id = blockIdx.x * blockDim.x + threadIdx.x;
    if (id >= 2 * nedges) return;
    const int ci = id / nedges;
    const int e  = id - ci * nedges;
    const int* row = (ci == 0 ? coo0 : coo1) + e * 3;
    const int dst = row[0], src = row[1], cnt = row[2];
    if (dst >= 0 && dst < T && cnt >= 0 && cnt < MX)
        srcs[ci * T * MX + dst * MX + cnt] = src;
}

// ---------------------------------------------------------------------------
// Kernel 3: sparse L1 attention. One thread per (coo, b, t, head).
// Logits <= 0 -> single-pass unnormalized softmax; divide at the end.
// ---------------------------------------------------------------------------
__global__ void sparse_kernel(const float* __restrict__ Q, const float* __restrict__ K,
                              const float* __restrict__ V, const int* __restrict__ srcs,
                              float* __restrict__ B) {
    const int id = blockIdx.x * blockDim.x + threadIdx.x;   // 2*BT*H = 131072
    const int h  = id & 3;
    const int bt = (id >> 2) & (BT - 1);
    const int ci = id >> 16;                                 // BT*H == 65536
    const int b  = bt >> 9;
    const int t  = bt & (T - 1);
    const int base = 20 * ci + h * 5;
    const int* sp  = srcs + ci * T * MX + t * MX;
    const float* qp = Q + bt * 64 + base;
    const float q0 = qp[0], q1 = qp[1], q2 = qp[2], q3 = qp[3], q4 = qp[4];
    const float iscale = 0.4472135954999579f;                // 1/sqrt(5)
    float l = 0.f, o0 = 0.f, o1 = 0.f, o2 = 0.f, o3 = 0.f, o4 = 0.f;
    #pragma unroll 4
    for (int c = 0; c < MX; ++c) {
        const int s = sp[c];
        if (s < 0) continue;                                 // empty slot (-1e12)
        const float* kp = K + (b * T + s) * 64 + base;
        float sum = fabsf(q0 - kp[0]) + fabsf(q1 - kp[1]) + fabsf(q2 - kp[2]) +
                    fabsf(q3 - kp[3]) + fabsf(q4 - kp[4]);
        const float e = expf(-sum * iscale);
        const float* vp = V + (b * T + s) * 64 + base;
        l  += e;
        o0 += e * vp[0]; o1 += e * vp[1]; o2 += e * vp[2];
        o3 += e * vp[3]; o4 += e * vp[4];
    }
    const float inv = (l > 0.f) ? 1.f / l : 0.f;
    float* bp = B + bt * 96 + 32 + base;
    bp[0] = o0 * inv; bp[1] = o1 * inv; bp[2] = o2 * inv;
    bp[3] = o3 * inv; bp[4] = o4 * inv;
}

// ---------------------------------------------------------------------------
// Kernel 4: dense L1 attention over the a2len a2a tokens, channels 72..95.
// Denominator includes the zero-pad key (padl > a2len): exp(-|q|_1/sqrt(6)).
// ---------------------------------------------------------------------------
__global__ void dense_kernel(const float* __restrict__ Q, const float* __restrict__ K,
                             const float* __restrict__ V, const int* __restrict__ a2a,
                             int a2len, int extra, float* __restrict__ B) {
    const int id = blockIdx.x * blockDim.x + threadIdx.x;
    if (id >= BS * 150 * H) return;
    const int h    = id & 3;
    const int rest = id >> 2;
    const int d    = rest % a2len;
    const int b    = rest / a2len;
    const int td   = a2a[d];
    const float scale = 0.4082482904638631f;                 // 1/sqrt(6)
    const float* qp = Q + (b * T + td) * 64 + 40 + h * 6;    // channel 72 -> idx 40
    float q[6];
    #pragma unroll
    for (int w = 0; w < 6; ++w) q[w] = qp[w];
    float l = 0.f, o[6] = {0.f, 0.f, 0.f, 0.f, 0.f, 0.f};
    for (int s = 0; s < a2len; ++s) {
        const int ts = a2a[s];
        const float* kp = K + (b * T + ts) * 64 + 40 + h * 6;
        float sum = 0.f;
        #pragma unroll
        for (int w = 0; w < 6; ++w) sum += fabsf(q[w] - kp[w]);
        const float e = expf(-sum * scale);
        l += e;
        const float* vp = V + (b * T + ts) * 64 + 40 + h * 6;
        #pragma unroll
        for (int w = 0; w < 6; ++w) o[w] += e * vp[w];
    }
    if (extra) {                                             // zero-pad key row
        float sum = 0.f;
        #pragma unroll
        for (int w = 0; w < 6; ++w) sum += fabsf(q[w]);
        l += expf(-sum * scale);
    }
    const float inv = 1.f / l;
    float* bp = B + (b * T + td) * 96 + 72 + h * 6;
    #pragma unroll
    for (int w = 0; w < 6; ++w) bp[w] = o[w] * inv;
}

// ---------------------------------------------------------------------------
// Kernel 5: yb = silu-gate(B); out = x + FWT^T @ yb + bias.
// Channels 0..31 of B are hard zeros -> silu contributes 0 -> inner loop
// only covers channels 32..95 (64 iters). 192 threads = 2 token-lanes x 96.
// ---------------------------------------------------------------------------
__global__ void fuse_kernel(const float* __restrict__ x, const float* __restrict__ FWT,
                            const float* __restrict__ B, float* __restrict__ out) {
    const int tid  = threadIdx.x;             // 0..191
    const int half = tid / 96;                // token-lane 0/1
    const int o    = tid - 96 * half;
    const int base = blockIdx.x * FUSE_TOK;   // grid = BT/FUSE_TOK
    __shared__ float yb[FUSE_TOK * 64];       // channels 32..95 only
    for (int idx = tid; idx < FUSE_TOK * 64; idx += 192) {
        const int j = idx >> 6, k = idx & 63;
        const float v = B[(base + j) * 96 + 32 + k];
        yb[idx] = v / (1.f + expf(-1.702f * v));
    }
    __syncthreads();
    float acc[FUSE_TOK / 2];
    const float bias = FWT[64 * 96 + o];
    #pragma unroll
    for (int j = 0; j < FUSE_TOK / 2; ++j) acc[j] = bias;
    #pragma unroll 4
    for (int i = 0; i < 64; ++i) {
        const float wv = FWT[i * 96 + o];
        #pragma unroll
        for (int j = 0; j < FUSE_TOK / 2; ++j) acc[j] += wv * yb[(2 * j + half) * 64 + i];
    }
    #pragma unroll
    for (int j = 0; j < FUSE_TOK / 2; ++j) {
        const int token = base + 2 * j + half;
        out[token * D + o] = x[token * D + o] + acc[j];
    }
}

// ---------------------------------------------------------------------------
extern "C" void kernel_launch(void* const* d_in, const int* in_sizes, int n_in,
                              void* d_out, int out_size, void* d_ws, size_t ws_size,
                              hipStream_t stream) {
    const float* x   = (const float*)d_in[0];
    const float* wqv = (const float*)d_in[1];
    const float* fw  = (const float*)d_in[2];
    const int*  coo0 = (const int*)d_in[3];
    const int*  coo1 = (const int*)d_in[4];
    const int*  a2a  = (const int*)d_in[5];
    const int a2len  = in_sizes[5];            // 150
    const int nedges = in_sizes[3] / 3;        // 16384

    // Workspace: Q | K | V | B | srcs(int) | WT | FWT   (~19.2 MB)
    float* Q   = (float*)d_ws;
    float* K   = Q + (size_t)BT * 64;
    float* V   = K + (size_t)BT * 64;
    float* Bb  = V + (size_t)BT * 64;
    int*  srcs = (int*)(Bb + (size_t)BT * 96);
    float* WT  = (float*)(srcs + 2 * T * MX);
    float* FWT = WT + 97 * 192;

    hipMemsetAsync(srcs, 0xFF, 2 * T * MX * sizeof(int), stream);  // -1 = empty
    hipMemsetAsync(Bb, 0, (size_t)BT * 96 * sizeof(float), stream);

    transpose_kernel<<<(97 * 192 + 65 * 96 + 255) / 256, 256, 0, stream>>>(wqv, fw, WT, FWT);
    qkv_kernel<<<BT / QKV_TOK, 192, 0, stream>>>(x, WT, Q, K, V);
    scatter_kernel<<<(2 * nedges + 255) / 256, 256, 0, stream>>>(coo0, coo1, srcs, nedges);
    sparse_kernel<<<(2 * BT * H) / 256, 256, 0, stream>>>(Q, K, V, srcs, Bb);
    const int padl  = (a2len + 15) / 16 * 16;
    const int extra = (padl > a2len) ? 1 : 0;
    dense_kernel<<<(BS * a2len * H + 255) / 256, 256, 0, stream>>>(Q, K, V, a2a, a2len, extra, Bb);
    fuse_kernel<<<BT / FUSE_TOK, 192, 0, stream>>>(x, FWT, Bb, (float*)d_out);
}

// Round 5
// 145.036 us; speedup vs baseline: 3.0413x; 1.2941x over previous
//
#include <hip/hip_runtime.h>
#include <hip/hip_bf16.h>
#include <math.h>

#define BS   32
#define T    512
#define BT   (BS * T)      // 16384 tokens
#define D    96
#define H    4
#define MX   32            // DST_MXLEN
#define A2MAX 160          // padl for a2len=150

#define QKV_TOK  8         // tokens per qkv block
#define FUSE_TOK 8         // tokens per fuse block
#define DT       32        // dst tokens per dense block

// ---------------------------------------------------------------------------
// Kernel 0: one-time weight transposes into workspace (both tiny).
// WT  [97][192]: WT[i*192 + p*64 + c] = wqv[(p*96+32+c)*97 + i]  (i=96 -> bias)
// FWT [65][96] : FWT[i*96 + o]        = fw[o*97 + 32 + i]        (i=64 -> bias)
// ---------------------------------------------------------------------------
__global__ void transpose_kernel(const float* __restrict__ wqv,
                                 const float* __restrict__ fw,
                                 float* __restrict__ WT, float* __restrict__ FWT) {
    int idx = blockIdx.x * blockDim.x + threadIdx.x;
    if (idx < 97 * 192) {
        const int i = idx / 192, oc = idx - 192 * i;
        const int p = oc >> 6, c = oc & 63;
        WT[idx] = wqv[(p * 96 + 32 + c) * 97 + i];
    }
    idx -= 97 * 192;
    if (idx >= 0 && idx < 65 * 96) {
        const int i = idx / 96, o = idx - 96 * i;
        FWT[idx] = fw[o * 97 + 32 + i];
    }
}

// ---------------------------------------------------------------------------
// Kernel 1: QKV projection, register-blocked. 192 threads x 8 tokens/block.
// One coalesced weight load (L2-resident) feeds 8 FMAs (x broadcast via LDS).
// Q/K/V layout: [(b*T+t)*64 + (ch-32)], fp32.
// ---------------------------------------------------------------------------
__global__ void qkv_kernel(const float* __restrict__ x, const float* __restrict__ WT,
                           float* __restrict__ Q, float* __restrict__ K,
                           float* __restrict__ V) {
    const int tid  = threadIdx.x;              // 0..191
    const int base = blockIdx.x * QKV_TOK;     // grid = BT/QKV_TOK
    __shared__ float xs[QKV_TOK * D];          // 768 floats
    #pragma unroll
    for (int j = 0; j < 4; ++j) xs[tid + 192 * j] = x[base * D + tid + 192 * j];
    __syncthreads();
    float acc[QKV_TOK];
    const float bias = WT[96 * 192 + tid];
    #pragma unroll
    for (int j = 0; j < QKV_TOK; ++j) acc[j] = bias;
    #pragma unroll 4
    for (int i = 0; i < D; ++i) {
        const float wv = WT[i * 192 + tid];
        #pragma unroll
        for (int j = 0; j < QKV_TOK; ++j) acc[j] += wv * xs[j * D + i];
    }
    const int part = tid >> 6, c = tid & 63;
    float* out = (part == 0) ? Q : (part == 1 ? K : V);
    #pragma unroll
    for (int j = 0; j < QKV_TOK; ++j) out[(base + j) * 64 + c] = acc[j];
}

// ---------------------------------------------------------------------------
// Kernel 2: scatter COO rows into a dense per-(token, slot) src table.
// srcs[(ci*T + dst)*MX + cnt] = src ; unwritten slots stay -1 (memset 0xFF).
// ---------------------------------------------------------------------------
__global__ void scatter_kernel(const int* __restrict__ coo0,
                               const int* __restrict__ coo1,
                               int* __restrict__ srcs, int nedges) {
    const int id = blockIdx.x * blockDim.x + threadIdx.x;
    if (id >= 2 * nedges) return;
    const int ci = id / nedges;
    const int e  = id - ci * nedges;
    const int* row = (ci == 0 ? coo0 : coo1) + e * 3;
    const int dst = row[0], src = row[1], cnt = row[2];
    if (dst >= 0 && dst < T && cnt >= 0 && cnt < MX)
        srcs[(ci * T + dst) * MX + cnt] = src;
}

// ---------------------------------------------------------------------------
// Kernel 3: sparse L1 attention, LDS-staged. One block per (b, ci, h):
// grid (8, 32) x 256 threads. K/V slice for ALL 512 src tokens staged in LDS
// (padded to 8 floats/token -> aligned float4 reads, banks 0/8/16/24).
// Each thread handles 2 dst tokens; 32-slot loop reads LDS, not L2.
// ---------------------------------------------------------------------------
__global__ void sparse_kernel(const float* __restrict__ Q, const float* __restrict__ K,
                              const float* __restrict__ V, const int* __restrict__ srcs,
                              float* __restrict__ B) {
    const int b   = blockIdx.y;
    const int ci  = blockIdx.x >> 2, h = blockIdx.x & 3;
    const int base = 20 * ci + h * 5;
    const int tid  = threadIdx.x;              // 256
    __shared__ float ks[T * 8];                // 16 KB
    __shared__ float vs[T * 8];                // 16 KB
    for (int i = tid; i < T * 5; i += 256) {
        const int s = i / 5, w = i - 5 * s;
        const int g = (b * T + s) * 64 + base + w;
        ks[s * 8 + w] = K[g];
        vs[s * 8 + w] = V[g];
    }
    __syncthreads();
    const float iscale = 0.4472135954999579f;  // 1/sqrt(5)
    for (int t = tid; t < T; t += 256) {
        const int* sp   = srcs + (ci * T + t) * MX;
        const float* qp = Q + (b * T + t) * 64 + base;
        const float q0 = qp[0], q1 = qp[1], q2 = qp[2], q3 = qp[3], q4 = qp[4];
        float l = 0.f, o0 = 0.f, o1 = 0.f, o2 = 0.f, o3 = 0.f, o4 = 0.f;
        #pragma unroll 4
        for (int c = 0; c < MX; ++c) {
            const int s = sp[c];
            if (s < 0) continue;               // empty slot (-1e12)
            const float4 k4 = *(const float4*)&ks[s * 8];
            const float  k5 = ks[s * 8 + 4];
            const float sum = fabsf(q0 - k4.x) + fabsf(q1 - k4.y) +
                              fabsf(q2 - k4.z) + fabsf(q3 - k4.w) + fabsf(q4 - k5);
            const float e = __expf(-sum * iscale);
            const float4 v4 = *(const float4*)&vs[s * 8];
            const float  v5 = vs[s * 8 + 4];
            l  += e;
            o0 += e * v4.x; o1 += e * v4.y; o2 += e * v4.z;
            o3 += e * v4.w; o4 += e * v5;
        }
        const float inv = (l > 0.f) ? 1.f / l : 0.f;
        float* bp = B + (b * T + t) * 96 + 32 + base;
        bp[0] = o0 * inv; bp[1] = o1 * inv; bp[2] = o2 * inv;
        bp[3] = o3 * inv; bp[4] = o4 * inv;
    }
}

// ---------------------------------------------------------------------------
// Kernel 4: dense L1 attention, LDS-staged. One block per (b, 32-dst tile):
// grid (ceil(a2len/DT), BS) x 128 threads (32 dl x 4 h). The 150 gathered
// K/V rows (24 ch, padded to 8/head) staged once in LDS; inner loop reads
// broadcast LDS. Denominator includes the zero-pad key (padl > a2len).
// ---------------------------------------------------------------------------
__global__ void dense_kernel(const float* __restrict__ Q, const float* __restrict__ K,
                             const float* __restrict__ V, const int* __restrict__ a2a,
                             int a2len, int extra, float* __restrict__ B) {
    const int b   = blockIdx.y;
    const int d0  = blockIdx.x * DT;
    const int tid = threadIdx.x;               // 128
    __shared__ int   rows[A2MAX];
    __shared__ float ks[A2MAX * 32];           // [s][h*8 + w], 20.5 KB
    __shared__ float vs[A2MAX * 32];
    for (int i = tid; i < a2len; i += 128) rows[i] = a2a[i];
    __syncthreads();
    for (int i = tid; i < a2len * 24; i += 128) {
        const int s = i / 24, w = i - 24 * s;
        const int hh = w / 6, ww = w - 6 * hh;
        const int g = (b * T + rows[s]) * 64 + 40 + w;   // channel 72 -> idx 40
        ks[s * 32 + hh * 8 + ww] = K[g];
        vs[s * 32 + hh * 8 + ww] = V[g];
    }
    __syncthreads();
    const int h = tid & 3, dl = tid >> 2;
    const int d = d0 + dl;
    if (d >= a2len) return;
    const int td = rows[d];
    const float scale = 0.4082482904638631f;   // 1/sqrt(6)
    const float* qp = Q + (b * T + td) * 64 + 40 + h * 6;
    const float q0 = qp[0], q1 = qp[1], q2 = qp[2],
                q3 = qp[3], q4 = qp[4], q5 = qp[5];
    float l = 0.f, o0 = 0.f, o1 = 0.f, o2 = 0.f, o3 = 0.f, o4 = 0.f, o5 = 0.f;
    for (int s = 0; s < a2len; ++s) {
        const float4 k4 = *(const float4*)&ks[s * 32 + h * 8];
        const float2 k2 = *(const float2*)&ks[s * 32 + h * 8 + 4];
        const float sum = fabsf(q0 - k4.x) + fabsf(q1 - k4.y) + fabsf(q2 - k4.z) +
                          fabsf(q3 - k4.w) + fabsf(q4 - k2.x) + fabsf(q5 - k2.y);
        const float e = __expf(-sum * scale);
        const float4 v4 = *(const float4*)&vs[s * 32 + h * 8];
        const float2 v2 = *(const float2*)&vs[s * 32 + h * 8 + 4];
        l  += e;
        o0 += e * v4.x; o1 += e * v4.y; o2 += e * v4.z;
        o3 += e * v4.w; o4 += e * v2.x; o5 += e * v2.y;
    }
    if (extra) {                               // zero-pad key row
        const float sum = fabsf(q0) + fabsf(q1) + fabsf(q2) +
                          fabsf(q3) + fabsf(q4) + fabsf(q5);
        l += __expf(-sum * scale);
    }
    const float inv = 1.f / l;
    float* bp = B + (b * T + td) * 96 + 72 + h * 6;
    bp[0] = o0 * inv; bp[1] = o1 * inv; bp[2] = o2 * inv;
    bp[3] = o3 * inv; bp[4] = o4 * inv; bp[5] = o5 * inv;
}

// ---------------------------------------------------------------------------
// Kernel 5: yb = silu-gate(B); out = x + FWT^T @ yb + bias.
// Channels 0..31 of B are hard zeros -> inner loop covers 32..95 only.
// ---------------------------------------------------------------------------
__global__ void fuse_kernel(const float* __restrict__ x, const float* __restrict__ FWT,
                            const float* __restrict__ B, float* __restrict__ out) {
    const int tid  = threadIdx.x;             // 0..191
    const int half = tid / 96;                // token-lane 0/1
    const int o    = tid - 96 * half;
    const int base = blockIdx.x * FUSE_TOK;   // grid = BT/FUSE_TOK
    __shared__ float yb[FUSE_TOK * 64];       // channels 32..95 only
    for (int idx = tid; idx < FUSE_TOK * 64; idx += 192) {
        const int j = idx >> 6, k = idx & 63;
        const float v = B[(base + j) * 96 + 32 + k];
        yb[idx] = v / (1.f + __expf(-1.702f * v));
    }
    __syncthreads();
    float acc[FUSE_TOK / 2];
    const float bias = FWT[64 * 96 + o];
    #pragma unroll
    for (int j = 0; j < FUSE_TOK / 2; ++j) acc[j] = bias;
    #pragma unroll 4
    for (int i = 0; i < 64; ++i) {
        const float wv = FWT[i * 96 + o];
        #pragma unroll
        for (int j = 0; j < FUSE_TOK / 2; ++j) acc[j] += wv * yb[(2 * j + half) * 64 + i];
    }
    #pragma unroll
    for (int j = 0; j < FUSE_TOK / 2; ++j) {
        const int token = base + 2 * j + half;
        out[token * D + o] = x[token * D + o] + acc[j];
    }
}

// ---------------------------------------------------------------------------
extern "C" void kernel_launch(void* const* d_in, const int* in_sizes, int n_in,
                              void* d_out, int out_size, void* d_ws, size_t ws_size,
                              hipStream_t stream) {
    const float* x   = (const float*)d_in[0];
    const float* wqv = (const float*)d_in[1];
    const float* fw  = (const float*)d_in[2];
    const int*  coo0 = (const int*)d_in[3];
    const int*  coo1 = (const int*)d_in[4];
    const int*  a2a  = (const int*)d_in[5];
    int a2len        = in_sizes[5];            // 150
    if (a2len > A2MAX) a2len = A2MAX;          // LDS capacity guard
    const int nedges = in_sizes[3] / 3;        // 16384

    // Workspace: Q | K | V | B | srcs(int) | WT | FWT   (~19.2 MB)
    float* Q   = (float*)d_ws;
    float* K   = Q + (size_t)BT * 64;
    float* V   = K + (size_t)BT * 64;
    float* Bb  = V + (size_t)BT * 64;
    int*  srcs = (int*)(Bb + (size_t)BT * 96);
    float* WT  = (float*)(srcs + 2 * T * MX);
    float* FWT = WT + 97 * 192;

    hipMemsetAsync(srcs, 0xFF, 2 * T * MX * sizeof(int), stream);  // -1 = empty
    hipMemsetAsync(Bb, 0, (size_t)BT * 96 * sizeof(float), stream);

    transpose_kernel<<<(97 * 192 + 65 * 96 + 255) / 256, 256, 0, stream>>>(wqv, fw, WT, FWT);
    qkv_kernel<<<BT / QKV_TOK, 192, 0, stream>>>(x, WT, Q, K, V);
    scatter_kernel<<<(2 * nedges + 255) / 256, 256, 0, stream>>>(coo0, coo1, srcs, nedges);
    sparse_kernel<<<dim3(8, BS), 256, 0, stream>>>(Q, K, V, srcs, Bb);
    const int padl  = (a2len + 15) / 16 * 16;
    const int extra = (padl > a2len) ? 1 : 0;
    dense_kernel<<<dim3((a2len + DT - 1) / DT, BS), 128, 0, stream>>>(Q, K, V, a2a, a2len, extra, Bb);
    fuse_kernel<<<BT / FUSE_TOK, 192, 0, stream>>>(x, FWT, Bb, (float*)d_out);
}

// Round 6
// 144.131 us; speedup vs baseline: 3.0604x; 1.0063x over previous
//
#include <hip/hip_runtime.h>
#include <hip/hip_bf16.h>
#include <math.h>

#define BS    32
#define T     512
#define BT    (BS * T)     // 16384 tokens
#define D     96
#define H     4
#define MX    32           // DST_MXLEN
#define A2MAX 160          // padl for a2len=150

#define QKV_TOK  16        // tokens per qkv block
#define FUSE_TOK 16        // tokens per fuse block
#define DT       32        // dst tokens per dense block

// ---------------------------------------------------------------------------
// Kernel 0 (prep): weight transposes + COO scatter + a2a position flags.
// WT  [97][192]: WT[i*192 + p*64 + c] = wqv[(p*96+32+c)*97 + i]  (i=96 -> bias)
// FWT [65][96] : FWT[i*96 + o]        = fw[o*97 + 32 + i]        (i=64 -> bias)
// srcs[(ci*T+dst)*MX + cnt] = src   (unwritten slots stay -1 from memset)
// flag[t] = position of t in a2a, or -1 (from memset).
// ---------------------------------------------------------------------------
__global__ void prep_kernel(const float* __restrict__ wqv, const float* __restrict__ fw,
                            const int* __restrict__ coo0, const int* __restrict__ coo1,
                            const int* __restrict__ a2a, int nedges, int a2len,
                            float* __restrict__ WT, float* __restrict__ FWT,
                            int* __restrict__ srcs, int* __restrict__ flag) {
    int idx = blockIdx.x * blockDim.x + threadIdx.x;
    if (idx < 97 * 192) {
        const int i = idx / 192, oc = idx - 192 * i;
        const int p = oc >> 6, c = oc & 63;
        WT[idx] = wqv[(p * 96 + 32 + c) * 97 + i];
        return;
    }
    idx -= 97 * 192;
    if (idx < 65 * 96) {
        const int i = idx / 96, o = idx - 96 * i;
        FWT[idx] = fw[o * 97 + 32 + i];
        return;
    }
    idx -= 65 * 96;
    if (idx < 2 * nedges) {
        const int ci = idx / nedges;
        const int e  = idx - ci * nedges;
        const int* row = (ci == 0 ? coo0 : coo1) + e * 3;
        const int dst = row[0], src = row[1], cnt = row[2];
        if (dst >= 0 && dst < T && cnt >= 0 && cnt < MX)
            srcs[(ci * T + dst) * MX + cnt] = src;
        return;
    }
    idx -= 2 * nedges;
    if (idx < a2len) flag[a2a[idx]] = idx;
}

// ---------------------------------------------------------------------------
// Kernel 1: QKV projection, 16-token register tile. 192 threads/block.
// K-loop in groups of 4: one float4 LDS broadcast feeds 4 FMAs per token.
// Epilogue also compacts a2a tokens' channels 72..95 of K/V into Kg/Vg
// ([b][pos][24], coalesced rows) for the dense kernel.
// ---------------------------------------------------------------------------
__global__ void qkv_kernel(const float* __restrict__ x, const float* __restrict__ WT,
                           const int* __restrict__ flag,
                           float* __restrict__ Q, float* __restrict__ K,
                           float* __restrict__ V,
                           float* __restrict__ Kg, float* __restrict__ Vg) {
    const int tid  = threadIdx.x;              // 0..191
    const int base = blockIdx.x * QKV_TOK;     // grid = BT/16; all tokens same b
    __shared__ float xs[QKV_TOK * D];          // 6 KB
    float4* xs4 = (float4*)xs;
    const float4* xg = (const float4*)(x + base * D);
    xs4[tid]       = xg[tid];
    xs4[tid + 192] = xg[tid + 192];
    __syncthreads();
    float acc[QKV_TOK];
    const float bias = WT[96 * 192 + tid];
    #pragma unroll
    for (int j = 0; j < QKV_TOK; ++j) acc[j] = bias;
    #pragma unroll 3
    for (int i4 = 0; i4 < 24; ++i4) {
        const float w0 = WT[(4 * i4 + 0) * 192 + tid];
        const float w1 = WT[(4 * i4 + 1) * 192 + tid];
        const float w2 = WT[(4 * i4 + 2) * 192 + tid];
        const float w3 = WT[(4 * i4 + 3) * 192 + tid];
        #pragma unroll
        for (int j = 0; j < QKV_TOK; ++j) {
            const float4 xv = xs4[j * 24 + i4];
            acc[j] += w0 * xv.x + w1 * xv.y + w2 * xv.z + w3 * xv.w;
        }
    }
    const int part = tid >> 6, c = tid & 63;
    float* out = (part == 0) ? Q : (part == 1 ? K : V);
    #pragma unroll
    for (int j = 0; j < QKV_TOK; ++j) out[(base + j) * 64 + c] = acc[j];
    if (part >= 1 && c >= 40) {                // channels 72..95 of K/V
        float* g = (part == 1) ? Kg : Vg;
        const int b = base >> 9;
        #pragma unroll
        for (int j = 0; j < QKV_TOK; ++j) {
            const int ps = flag[(base + j) & (T - 1)];
            if (ps >= 0) g[(b * A2MAX + ps) * 24 + (c - 40)] = acc[j];
        }
    }
}

// ---------------------------------------------------------------------------
// Kernel 2: sparse L1 attention, LDS-staged. Block per (b, ci, h, t-half):
// grid (8, 32, 2) x 256. K/V slice for all 512 src tokens in LDS, layout
// [w][T] -> bank = s%32 (random s ~2-way, free). srcs loaded as int4.
// ---------------------------------------------------------------------------
__global__ void sparse_kernel(const float* __restrict__ Q, const float* __restrict__ K,
                              const float* __restrict__ V, const int* __restrict__ srcs,
                              float* __restrict__ B) {
    const int b   = blockIdx.y;
    const int ci  = blockIdx.x >> 2, h = blockIdx.x & 3;
    const int base = 20 * ci + h * 5;
    const int tid  = threadIdx.x;              // 256
    __shared__ float ks[5 * T];                // 10 KB
    __shared__ float vs[5 * T];                // 10 KB
    for (int i = tid; i < 5 * T; i += 256) {
        const int s = i & (T - 1), w = i >> 9;
        const int g = (b * T + s) * 64 + base + w;
        ks[w * T + s] = K[g];
        vs[w * T + s] = V[g];
    }
    __syncthreads();
    const float iscale = 0.4472135954999579f;  // 1/sqrt(5)
    const int t = blockIdx.z * 256 + tid;
    const int4* sp4 = (const int4*)(srcs + (ci * T + t) * MX);
    const float* qp = Q + (b * T + t) * 64 + base;
    const float q0 = qp[0], q1 = qp[1], q2 = qp[2], q3 = qp[3], q4 = qp[4];
    float l = 0.f, o0 = 0.f, o1 = 0.f, o2 = 0.f, o3 = 0.f, o4 = 0.f;
    #pragma unroll 2
    for (int c4 = 0; c4 < MX / 4; ++c4) {
        const int4 s4 = sp4[c4];
        const int sv[4] = {s4.x, s4.y, s4.z, s4.w};
        #pragma unroll
        for (int m = 0; m < 4; ++m) {
            const int s = sv[m];
            if (s < 0) continue;               // empty slot (-1e12)
            const float sum = fabsf(q0 - ks[s]) + fabsf(q1 - ks[T + s]) +
                              fabsf(q2 - ks[2 * T + s]) + fabsf(q3 - ks[3 * T + s]) +
                              fabsf(q4 - ks[4 * T + s]);
            const float e = __expf(-sum * iscale);
            l  += e;
            o0 += e * vs[s];         o1 += e * vs[T + s];
            o2 += e * vs[2 * T + s]; o3 += e * vs[3 * T + s];
            o4 += e * vs[4 * T + s];
        }
    }
    const float inv = (l > 0.f) ? 1.f / l : 0.f;
    float* bp = B + (b * T + t) * 96 + 32 + base;
    bp[0] = o0 * inv; bp[1] = o1 * inv; bp[2] = o2 * inv;
    bp[3] = o3 * inv; bp[4] = o4 * inv;
}

// ---------------------------------------------------------------------------
// Kernel 3: dense L1 attention over a2len tokens, channels 72..95.
// Stages the COMPACT Kg/Vg (coalesced float4) into LDS padded [s][32]
// (inner-loop reads are uniform-s broadcasts -> conflict-free b128).
// Denominator includes the zero-pad key (padl > a2len).
// ---------------------------------------------------------------------------
__global__ void dense_kernel(const float* __restrict__ Q,
                             const float* __restrict__ Kg, const float* __restrict__ Vg,
                             const int* __restrict__ a2a,
                             int a2len, int extra, float* __restrict__ B) {
    const int b   = blockIdx.y;
    const int d0  = blockIdx.x * DT;
    const int tid = threadIdx.x;               // 128
    __shared__ int   rows[A2MAX];
    __shared__ float ks[A2MAX * 32];           // 20.5 KB
    __shared__ float vs[A2MAX * 32];
    for (int i = tid; i < a2len; i += 128) rows[i] = a2a[i];
    const int nq = (a2len * 24) / 4;           // 900 float4s
    const float4* kg4 = (const float4*)(Kg + (size_t)b * A2MAX * 24);
    const float4* vg4 = (const float4*)(Vg + (size_t)b * A2MAX * 24);
    for (int idx = tid; idx < nq; idx += 128) {
        const int s = idx / 6, r = idx - 6 * s;
        const float4 kk = kg4[idx];
        const float4 vv = vg4[idx];
        const float kv[4] = {kk.x, kk.y, kk.z, kk.w};
        const float vv4[4] = {vv.x, vv.y, vv.z, vv.w};
        #pragma unroll
        for (int m = 0; m < 4; ++m) {
            const int w = r * 4 + m, hh = w / 6, ww = w - 6 * hh;
            ks[s * 32 + hh * 8 + ww] = kv[m];
            vs[s * 32 + hh * 8 + ww] = vv4[m];
        }
    }
    __syncthreads();
    const int h = tid & 3, dl = tid >> 2;
    const int d = d0 + dl;
    if (d >= a2len) return;
    const int td = rows[d];
    const float scale = 0.4082482904638631f;   // 1/sqrt(6)
    const float* qp = Q + (b * T + td) * 64 + 40 + h * 6;
    const float q0 = qp[0], q1 = qp[1], q2 = qp[2],
                q3 = qp[3], q4 = qp[4], q5 = qp[5];
    float l = 0.f, o0 = 0.f, o1 = 0.f, o2 = 0.f, o3 = 0.f, o4 = 0.f, o5 = 0.f;
    for (int s = 0; s < a2len; ++s) {
        const float4 k4 = *(const float4*)&ks[s * 32 + h * 8];
        const float2 k2 = *(const float2*)&ks[s * 32 + h * 8 + 4];
        const float sum = fabsf(q0 - k4.x) + fabsf(q1 - k4.y) + fabsf(q2 - k4.z) +
                          fabsf(q3 - k4.w) + fabsf(q4 - k2.x) + fabsf(q5 - k2.y);
        const float e = __expf(-sum * scale);
        const float4 v4 = *(const float4*)&vs[s * 32 + h * 8];
        const float2 v2 = *(const float2*)&vs[s * 32 + h * 8 + 4];
        l  += e;
        o0 += e * v4.x; o1 += e * v4.y; o2 += e * v4.z;
        o3 += e * v4.w; o4 += e * v2.x; o5 += e * v2.y;
    }
    if (extra) {                               // zero-pad key row
        const float sum = fabsf(q0) + fabsf(q1) + fabsf(q2) +
                          fabsf(q3) + fabsf(q4) + fabsf(q5);
        l += __expf(-sum * scale);
    }
    const float inv = 1.f / l;
    float* bp = B + (b * T + td) * 96 + 72 + h * 6;
    bp[0] = o0 * inv; bp[1] = o1 * inv; bp[2] = o2 * inv;
    bp[3] = o3 * inv; bp[4] = o4 * inv; bp[5] = o5 * inv;
}

// ---------------------------------------------------------------------------
// Kernel 4: yb = silu-gate(B); out = x + FWT^T @ yb + bias. 16-token tile.
// Channels 0..31 of B are hard zeros -> loop covers 32..95 only. Dense
// channels (>=72) of non-a2a tokens were never written -> masked via flag.
// ---------------------------------------------------------------------------
__global__ void fuse_kernel(const float* __restrict__ x, const float* __restrict__ FWT,
                            const float* __restrict__ B, const int* __restrict__ flag,
                            float* __restrict__ out) {
    const int tid  = threadIdx.x;              // 0..191
    const int half = tid / 96;                 // token-lane 0/1
    const int o    = tid - 96 * half;
    const int base = blockIdx.x * FUSE_TOK;    // grid = BT/16
    __shared__ float yb[FUSE_TOK * 64];        // 4 KB, channels 32..95
    float4* yb4 = (float4*)yb;
    for (int idx = tid; idx < FUSE_TOK * 64; idx += 192) {
        const int j = idx >> 6, k = idx & 63;
        float v = B[(base + j) * 96 + 32 + k];
        if (k >= 40 && flag[(base + j) & (T - 1)] < 0) v = 0.f;  // unwritten dense ch
        yb[idx] = v / (1.f + __expf(-1.702f * v));
    }
    __syncthreads();
    float acc[FUSE_TOK / 2];
    const float bias = FWT[64 * 96 + o];
    #pragma unroll
    for (int j = 0; j < FUSE_TOK / 2; ++j) acc[j] = bias;
    #pragma unroll 2
    for (int i4 = 0; i4 < 16; ++i4) {
        const float w0 = FWT[(4 * i4 + 0) * 96 + o];
        const float w1 = FWT[(4 * i4 + 1) * 96 + o];
        const float w2 = FWT[(4 * i4 + 2) * 96 + o];
        const float w3 = FWT[(4 * i4 + 3) * 96 + o];
        #pragma unroll
        for (int j = 0; j < FUSE_TOK / 2; ++j) {
            const float4 yv = yb4[(2 * j + half) * 16 + i4];
            acc[j] += w0 * yv.x + w1 * yv.y + w2 * yv.z + w3 * yv.w;
        }
    }
    #pragma unroll
    for (int j = 0; j < FUSE_TOK / 2; ++j) {
        const int token = base + 2 * j + half;
        out[token * D + o] = x[token * D + o] + acc[j];
    }
}

// ---------------------------------------------------------------------------
extern "C" void kernel_launch(void* const* d_in, const int* in_sizes, int n_in,
                              void* d_out, int out_size, void* d_ws, size_t ws_size,
                              hipStream_t stream) {
    const float* x   = (const float*)d_in[0];
    const float* wqv = (const float*)d_in[1];
    const float* fw  = (const float*)d_in[2];
    const int*  coo0 = (const int*)d_in[3];
    const int*  coo1 = (const int*)d_in[4];
    const int*  a2a  = (const int*)d_in[5];
    int a2len        = in_sizes[5];            // 150
    if (a2len > A2MAX) a2len = A2MAX;          // LDS/scratch capacity guard
    const int nedges = in_sizes[3] / 3;        // 16384

    // Workspace: Q|K|V (BT*64) | Bb (BT*96) | Kg|Vg (BS*A2MAX*24) |
    //            srcs (2*T*MX) | flag (T) | WT (97*192) | FWT (65*96)
    float* Q   = (float*)d_ws;
    float* K   = Q  + (size_t)BT * 64;
    float* V   = K  + (size_t)BT * 64;
    float* Bb  = V  + (size_t)BT * 64;
    float* Kg  = Bb + (size_t)BT * 96;
    float* Vg  = Kg + (size_t)BS * A2MAX * 24;
    int*  srcs = (int*)(Vg + (size_t)BS * A2MAX * 24);
    int*  flag = srcs + 2 * T * MX;
    float* WT  = (float*)(flag + T);
    float* FWT = WT + 97 * 192;

    // srcs slots and flags both initialized to -1 in ONE fill.
    hipMemsetAsync(srcs, 0xFF, (2 * T * MX + T) * sizeof(int), stream);

    const int prep_n = 97 * 192 + 65 * 96 + 2 * nedges + a2len;
    prep_kernel<<<(prep_n + 255) / 256, 256, 0, stream>>>(
        wqv, fw, coo0, coo1, a2a, nedges, a2len, WT, FWT, srcs, flag);
    qkv_kernel<<<BT / QKV_TOK, 192, 0, stream>>>(x, WT, flag, Q, K, V, Kg, Vg);
    sparse_kernel<<<dim3(8, BS, 2), 256, 0, stream>>>(Q, K, V, srcs, Bb);
    const int padl  = (a2len + 15) / 16 * 16;
    const int extra = (padl > a2len) ? 1 : 0;
    dense_kernel<<<dim3((a2len + DT - 1) / DT, BS), 128, 0, stream>>>(
        Q, Kg, Vg, a2a, a2len, extra, Bb);
    fuse_kernel<<<BT / FUSE_TOK, 192, 0, stream>>>(x, FWT, Bb, flag, (float*)d_out);
}

// Round 7
// 131.586 us; speedup vs baseline: 3.3521x; 1.0953x over previous
//
#include <hip/hip_runtime.h>
#include <hip/hip_bf16.h>
#include <math.h>

#define BS    32
#define T     512
#define BT    (BS * T)     // 16384 tokens
#define D     96
#define H     4
#define MX    32           // DST_MXLEN
#define A2MAX 160          // padl for a2len=150

#define QKV_TOK  16        // tokens per qkv block
#define FUSE_TOK 16        // tokens per fuse block
#define DT       32        // dst tokens per dense block

// ---------------------------------------------------------------------------
// Kernel 0 (prep): weight transposes + COO scatter + a2a position flags.
// WT  [97][192]: WT[i*192 + p*64 + c] = wqv[(p*96+32+c)*97 + i]  (i=96 -> bias)
// FWT [65][96] : FWT[i*96 + o]        = fw[o*97 + 32 + i]        (i=64 -> bias)
// srcs[(ci*T+dst)*MX + cnt] = src   (unwritten slots stay -1 from memset)
// flag[t] = position of t in a2a, or -1 (from memset).
// ---------------------------------------------------------------------------
__global__ void prep_kernel(const float* __restrict__ wqv, const float* __restrict__ fw,
                            const int* __restrict__ coo0, const int* __restrict__ coo1,
                            const int* __restrict__ a2a, int nedges, int a2len,
                            float* __restrict__ WT, float* __restrict__ FWT,
                            int* __restrict__ srcs, int* __restrict__ flag) {
    int idx = blockIdx.x * blockDim.x + threadIdx.x;
    if (idx < 97 * 192) {
        const int i = idx / 192, oc = idx - 192 * i;
        const int p = oc >> 6, c = oc & 63;
        WT[idx] = wqv[(p * 96 + 32 + c) * 97 + i];
        return;
    }
    idx -= 97 * 192;
    if (idx < 65 * 96) {
        const int i = idx / 96, o = idx - 96 * i;
        FWT[idx] = fw[o * 97 + 32 + i];
        return;
    }
    idx -= 65 * 96;
    if (idx < 2 * nedges) {
        const int ci = idx / nedges;
        const int e  = idx - ci * nedges;
        const int* row = (ci == 0 ? coo0 : coo1) + e * 3;
        const int dst = row[0], src = row[1], cnt = row[2];
        if (dst >= 0 && dst < T && cnt >= 0 && cnt < MX)
            srcs[(ci * T + dst) * MX + cnt] = src;
        return;
    }
    idx -= 2 * nedges;
    if (idx < a2len) flag[a2a[idx]] = idx;
}

// ---------------------------------------------------------------------------
// Kernel 1: QKV projection, 16-token register tile, 192 threads/block.
// Outputs (no token-major QKV at all):
//  - sparse channels (c<40, i.e. model ch 32..71) channel-major:
//      XS[((c)*BS + b)*T + t]   -> coalesced staging for sparse_kernel
//  - dense channels (c>=40, ch 72..95) compacted for a2a tokens:
//      Xg[(b*A2MAX + pos)*24 + (c-40)]
// ---------------------------------------------------------------------------
__global__ void qkv_kernel(const float* __restrict__ x, const float* __restrict__ WT,
                           const int* __restrict__ flag,
                           float* __restrict__ QS, float* __restrict__ KS,
                           float* __restrict__ VS,
                           float* __restrict__ Qg, float* __restrict__ Kg,
                           float* __restrict__ Vg) {
    const int tid  = threadIdx.x;              // 0..191
    const int base = blockIdx.x * QKV_TOK;     // grid = BT/16; all tokens same b
    __shared__ float xs[QKV_TOK * D];          // 6 KB
    float4* xs4 = (float4*)xs;
    const float4* xg = (const float4*)(x + base * D);
    xs4[tid]       = xg[tid];
    xs4[tid + 192] = xg[tid + 192];
    __syncthreads();
    float acc[QKV_TOK];
    const float bias = WT[96 * 192 + tid];
    #pragma unroll
    for (int j = 0; j < QKV_TOK; ++j) acc[j] = bias;
    #pragma unroll 3
    for (int i4 = 0; i4 < 24; ++i4) {
        const float w0 = WT[(4 * i4 + 0) * 192 + tid];
        const float w1 = WT[(4 * i4 + 1) * 192 + tid];
        const float w2 = WT[(4 * i4 + 2) * 192 + tid];
        const float w3 = WT[(4 * i4 + 3) * 192 + tid];
        #pragma unroll
        for (int j = 0; j < QKV_TOK; ++j) {
            const float4 xv = xs4[j * 24 + i4];
            acc[j] += w0 * xv.x + w1 * xv.y + w2 * xv.z + w3 * xv.w;
        }
    }
    const int part = tid >> 6, c = tid & 63;
    const int b    = base >> 9;
    const int tloc = base & (T - 1);
    if (c < 40) {                              // sparse channels, channel-major
        float* XS = (part == 0) ? QS : (part == 1 ? KS : VS);
        float4* dp = (float4*)(XS + ((size_t)c * BS + b) * T + tloc);
        #pragma unroll
        for (int m = 0; m < 4; ++m)
            dp[m] = make_float4(acc[4 * m], acc[4 * m + 1],
                                acc[4 * m + 2], acc[4 * m + 3]);
    } else {                                   // dense channels, compact a2a rows
        float* g = (part == 0) ? Qg : (part == 1 ? Kg : Vg);
        #pragma unroll
        for (int j = 0; j < QKV_TOK; ++j) {
            const int ps = flag[tloc + j];
            if (ps >= 0) g[((size_t)b * A2MAX + ps) * 24 + (c - 40)] = acc[j];
        }
    }
}

// ---------------------------------------------------------------------------
// Kernel 2: sparse L1 attention. One block per (b, ci, h): grid (8, 32) x 512.
// Staging from channel-major KS/VS is FULLY coalesced (contiguous in t).
// LDS layout [w][T]: inner-loop bank = s%32, random s ~2-way = free (m136).
// Each thread handles exactly one dst token t = tid.
// ---------------------------------------------------------------------------
__global__ void sparse_kernel(const float* __restrict__ QS, const float* __restrict__ KS,
                              const float* __restrict__ VS, const int* __restrict__ srcs,
                              float* __restrict__ B) {
    const int b   = blockIdx.y;
    const int ci  = blockIdx.x >> 2, h = blockIdx.x & 3;
    const int cb  = 20 * ci + 5 * h;           // channel base within the 40
    const int tid = threadIdx.x;               // 512 = T
    __shared__ float ks[5 * T];                // 10 KB
    __shared__ float vs[5 * T];                // 10 KB
    const size_t rowbase = ((size_t)cb * BS + b) * T;
    #pragma unroll
    for (int i = tid; i < 5 * T; i += 512) {
        const int w = i >> 9, s = i & (T - 1);
        ks[i] = KS[rowbase + (size_t)w * BS * T + s];
        vs[i] = VS[rowbase + (size_t)w * BS * T + s];
    }
    __syncthreads();
    const float iscale = 0.4472135954999579f;  // 1/sqrt(5)
    const int t = tid;
    const float q0 = QS[rowbase + 0 * BS * T + t];
    const float q1 = QS[rowbase + 1 * BS * T + t];
    const float q2 = QS[rowbase + 2 * BS * T + t];
    const float q3 = QS[rowbase + 3 * BS * T + t];
    const float q4 = QS[rowbase + 4 * BS * T + t];
    const int4* sp4 = (const int4*)(srcs + (ci * T + t) * MX);
    float l = 0.f, o0 = 0.f, o1 = 0.f, o2 = 0.f, o3 = 0.f, o4 = 0.f;
    #pragma unroll 2
    for (int c4 = 0; c4 < MX / 4; ++c4) {
        const int4 s4 = sp4[c4];
        const int sv[4] = {s4.x, s4.y, s4.z, s4.w};
        #pragma unroll
        for (int m = 0; m < 4; ++m) {
            const int s = sv[m];
            if (s < 0) continue;               // empty slot (-1e12)
            const float sum = fabsf(q0 - ks[s]) + fabsf(q1 - ks[T + s]) +
                              fabsf(q2 - ks[2 * T + s]) + fabsf(q3 - ks[3 * T + s]) +
                              fabsf(q4 - ks[4 * T + s]);
            const float e = __expf(-sum * iscale);
            l  += e;
            o0 += e * vs[s];         o1 += e * vs[T + s];
            o2 += e * vs[2 * T + s]; o3 += e * vs[3 * T + s];
            o4 += e * vs[4 * T + s];
        }
    }
    const float inv = (l > 0.f) ? 1.f / l : 0.f;
    float* bp = B + ((size_t)b * T + t) * 96 + 32 + cb;
    bp[0] = o0 * inv; bp[1] = o1 * inv; bp[2] = o2 * inv;
    bp[3] = o3 * inv; bp[4] = o4 * inv;
}

// ---------------------------------------------------------------------------
// Kernel 3: dense L1 attention over a2len tokens, channels 72..95.
// K/V staged from compact Kg/Vg (coalesced float4) into LDS [s][h*8+w]
// (uniform-s broadcast reads -> conflict-free b128). Q read from compact Qg.
// Denominator includes the zero-pad key (padl > a2len).
// ---------------------------------------------------------------------------
__global__ void dense_kernel(const float* __restrict__ Qg,
                             const float* __restrict__ Kg, const float* __restrict__ Vg,
                             const int* __restrict__ a2a,
                             int a2len, int extra, float* __restrict__ B) {
    const int b   = blockIdx.y;
    const int d0  = blockIdx.x * DT;
    const int tid = threadIdx.x;               // 128
    __shared__ int   rows[A2MAX];
    __shared__ float ks[A2MAX * 32];           // 20.5 KB
    __shared__ float vs[A2MAX * 32];
    for (int i = tid; i < a2len; i += 128) rows[i] = a2a[i];
    const int nq = (a2len * 24) / 4;           // 900 float4s
    const float4* kg4 = (const float4*)(Kg + (size_t)b * A2MAX * 24);
    const float4* vg4 = (const float4*)(Vg + (size_t)b * A2MAX * 24);
    for (int idx = tid; idx < nq; idx += 128) {
        const int s = idx / 6, r = idx - 6 * s;
        const float4 kk = kg4[idx];
        const float4 vv = vg4[idx];
        const float kv[4]  = {kk.x, kk.y, kk.z, kk.w};
        const float vv4[4] = {vv.x, vv.y, vv.z, vv.w};
        #pragma unroll
        for (int m = 0; m < 4; ++m) {
            const int w = r * 4 + m, hh = w / 6, ww = w - 6 * hh;
            ks[s * 32 + hh * 8 + ww] = kv[m];
            vs[s * 32 + hh * 8 + ww] = vv4[m];
        }
    }
    __syncthreads();
    const int h = tid & 3, dl = tid >> 2;
    const int d = d0 + dl;
    if (d >= a2len) return;
    const float scale = 0.4082482904638631f;   // 1/sqrt(6)
    const float* qp = Qg + ((size_t)b * A2MAX + d) * 24 + h * 6;
    const float q0 = qp[0], q1 = qp[1], q2 = qp[2],
                q3 = qp[3], q4 = qp[4], q5 = qp[5];
    float l = 0.f, o0 = 0.f, o1 = 0.f, o2 = 0.f, o3 = 0.f, o4 = 0.f, o5 = 0.f;
    for (int s = 0; s < a2len; ++s) {
        const float4 k4 = *(const float4*)&ks[s * 32 + h * 8];
        const float2 k2 = *(const float2*)&ks[s * 32 + h * 8 + 4];
        const float sum = fabsf(q0 - k4.x) + fabsf(q1 - k4.y) + fabsf(q2 - k4.z) +
                          fabsf(q3 - k4.w) + fabsf(q4 - k2.x) + fabsf(q5 - k2.y);
        const float e = __expf(-sum * scale);
        const float4 v4 = *(const float4*)&vs[s * 32 + h * 8];
        const float2 v2 = *(const float2*)&vs[s * 32 + h * 8 + 4];
        l  += e;
        o0 += e * v4.x; o1 += e * v4.y; o2 += e * v4.z;
        o3 += e * v4.w; o4 += e * v2.x; o5 += e * v2.y;
    }
    if (extra) {                               // zero-pad key row
        const float sum = fabsf(q0) + fabsf(q1) + fabsf(q2) +
                          fabsf(q3) + fabsf(q4) + fabsf(q5);
        l += __expf(-sum * scale);
    }
    const float inv = 1.f / l;
    float* bp = B + ((size_t)b * T + rows[d]) * 96 + 72 + h * 6;
    bp[0] = o0 * inv; bp[1] = o1 * inv; bp[2] = o2 * inv;
    bp[3] = o3 * inv; bp[4] = o4 * inv; bp[5] = o5 * inv;
}

// ---------------------------------------------------------------------------
// Kernel 4: yb = silu-gate(B); out = x + FWT^T @ yb + bias. 16-token tile.
// Channels 0..31 of B are hard zeros -> loop covers 32..95 only. Dense
// channels (>=72) of non-a2a tokens were never written -> masked via flag.
// ---------------------------------------------------------------------------
__global__ void fuse_kernel(const float* __restrict__ x, const float* __restrict__ FWT,
                            const float* __restrict__ B, const int* __restrict__ flag,
                            float* __restrict__ out) {
    const int tid  = threadIdx.x;              // 0..191
    const int half = tid / 96;                 // token-lane 0/1
    const int o    = tid - 96 * half;
    const int base = blockIdx.x * FUSE_TOK;    // grid = BT/16
    __shared__ float yb[FUSE_TOK * 64];        // 4 KB, channels 32..95
    float4* yb4 = (float4*)yb;
    for (int idx = tid; idx < FUSE_TOK * 64; idx += 192) {
        const int j = idx >> 6, k = idx & 63;
        float v = B[(base + j) * 96 + 32 + k];
        if (k >= 40 && flag[(base + j) & (T - 1)] < 0) v = 0.f;  // unwritten dense ch
        yb[idx] = v / (1.f + __expf(-1.702f * v));
    }
    __syncthreads();
    float acc[FUSE_TOK / 2];
    const float bias = FWT[64 * 96 + o];
    #pragma unroll
    for (int j = 0; j < FUSE_TOK / 2; ++j) acc[j] = bias;
    #pragma unroll 2
    for (int i4 = 0; i4 < 16; ++i4) {
        const float w0 = FWT[(4 * i4 + 0) * 96 + o];
        const float w1 = FWT[(4 * i4 + 1) * 96 + o];
        const float w2 = FWT[(4 * i4 + 2) * 96 + o];
        const float w3 = FWT[(4 * i4 + 3) * 96 + o];
        #pragma unroll
        for (int j = 0; j < FUSE_TOK / 2; ++j) {
            const float4 yv = yb4[(2 * j + half) * 16 + i4];
            acc[j] += w0 * yv.x + w1 * yv.y + w2 * yv.z + w3 * yv.w;
        }
    }
    #pragma unroll
    for (int j = 0; j < FUSE_TOK / 2; ++j) {
        const int token = base + 2 * j + half;
        out[token * D + o] = x[token * D + o] + acc[j];
    }
}

// ---------------------------------------------------------------------------
extern "C" void kernel_launch(void* const* d_in, const int* in_sizes, int n_in,
                              void* d_out, int out_size, void* d_ws, size_t ws_size,
                              hipStream_t stream) {
    const float* x   = (const float*)d_in[0];
    const float* wqv = (const float*)d_in[1];
    const float* fw  = (const float*)d_in[2];
    const int*  coo0 = (const int*)d_in[3];
    const int*  coo1 = (const int*)d_in[4];
    const int*  a2a  = (const int*)d_in[5];
    int a2len        = in_sizes[5];            // 150
    if (a2len > A2MAX) a2len = A2MAX;          // LDS/scratch capacity guard
    const int nedges = in_sizes[3] / 3;        // 16384

    // Workspace: QS|KS|VS (40*BS*T each) | Bb (BT*96) | Qg|Kg|Vg | srcs | flag | WT | FWT
    float* QS  = (float*)d_ws;
    float* KS  = QS + (size_t)40 * BS * T;
    float* VS  = KS + (size_t)40 * BS * T;
    float* Bb  = VS + (size_t)40 * BS * T;
    float* Qg  = Bb + (size_t)BT * 96;
    float* Kg  = Qg + (size_t)BS * A2MAX * 24;
    float* Vg  = Kg + (size_t)BS * A2MAX * 24;
    int*  srcs = (int*)(Vg + (size_t)BS * A2MAX * 24);
    int*  flag = srcs + 2 * T * MX;
    float* WT  = (float*)(flag + T);
    float* FWT = WT + 97 * 192;

    // srcs slots and flags both initialized to -1 in ONE fill.
    hipMemsetAsync(srcs, 0xFF, (2 * T * MX + T) * sizeof(int), stream);

    const int prep_n = 97 * 192 + 65 * 96 + 2 * nedges + a2len;
    prep_kernel<<<(prep_n + 255) / 256, 256, 0, stream>>>(
        wqv, fw, coo0, coo1, a2a, nedges, a2len, WT, FWT, srcs, flag);
    qkv_kernel<<<BT / QKV_TOK, 192, 0, stream>>>(x, WT, flag, QS, KS, VS, Qg, Kg, Vg);
    sparse_kernel<<<dim3(8, BS), 512, 0, stream>>>(QS, KS, VS, srcs, Bb);
    const int padl  = (a2len + 15) / 16 * 16;
    const int extra = (padl > a2len) ? 1 : 0;
    dense_kernel<<<dim3((a2len + DT - 1) / DT, BS), 128, 0, stream>>>(
        Qg, Kg, Vg, a2a, a2len, extra, Bb);
    fuse_kernel<<<BT / FUSE_TOK, 192, 0, stream>>>(x, FWT, Bb, flag, (float*)d_out);
}